// Round 5
// baseline (193.102 us; speedup 1.0000x reference)
//
#include <hip/hip_runtime.h>
#include <hip/hip_bf16.h>

#define NB 4
#define SEQ 2048
#define NHEADS 8

typedef __attribute__((ext_vector_type(8))) short bf16x8;
typedef __attribute__((ext_vector_type(4))) short bf16x4;
typedef __attribute__((ext_vector_type(4))) float f32x4;

__device__ inline short f2bf(float x) {
    union { float f; unsigned u; } v; v.f = x;
    unsigned r = v.u + 0x7FFF + ((v.u >> 16) & 1);
    return (short)(r >> 16);
}

__device__ inline unsigned pack2bf(float a, float b) {
    __hip_bfloat162 h = __float22bfloat162_rn(make_float2(a, b));
    unsigned u; __builtin_memcpy(&u, &h, 4);
    return u;
}

__device__ inline bf16x8 pack8(float4 a, float4 b) {
    union { unsigned u[4]; bf16x8 v; } r;
    r.u[0] = pack2bf(a.x, a.y);
    r.u[1] = pack2bf(a.z, a.w);
    r.u[2] = pack2bf(b.x, b.y);
    r.u[3] = pack2bf(b.z, b.w);
    return r.v;
}

// ---------------------------------------------------------------------------
// 128x128-tile bf16 MFMA GEMM, optional fused fp32->bf16 conversion of A/W.
// out[r][c] = (sum_k A[r][k]*W[c][k] + bias[c]) * scale
// 256 thr = 4 waves (2x2); XOR-swizzled unpadded LDS; register prefetch.
// ---------------------------------------------------------------------------
template <bool CVT_A, bool CVT_W, bool OUT_BF16>
__global__ __launch_bounds__(256) void gemm128(
    const void* __restrict__ A_, const void* __restrict__ W_,
    const float* __restrict__ bias, void* __restrict__ out,
    int K, int Ccols, float scale)
{
    __shared__ short As[128 * 64];
    __shared__ short Ws[128 * 64];
    const int tid = threadIdx.x;
    const int w = tid >> 6, lane = tid & 63, low = lane & 15, quad = lane >> 4;
    const int wm = w >> 1, wn = w & 1;
    const int rM0 = blockIdx.y * 128, c0 = blockIdx.x * 128;
    const int srow = tid >> 3, sj = tid & 7;

    f32x4 acc[4][4];
#pragma unroll
    for (int mt = 0; mt < 4; ++mt)
#pragma unroll
        for (int nt = 0; nt < 4; ++nt) acc[mt][nt] = (f32x4){0.f, 0.f, 0.f, 0.f};

    float4 paf[4][2], pwf[4][2];
    bf16x8 pab[4], pwb[4];

    auto loadA = [&](int c, int k0) {
        const int row = c * 32 + srow;
        if constexpr (CVT_A) {
            const float* p = (const float*)A_ + (size_t)(rM0 + row) * K + k0 + sj * 8;
            paf[c][0] = ((const float4*)p)[0];
            paf[c][1] = ((const float4*)p)[1];
        } else {
            pab[c] = *(const bf16x8*)((const short*)A_ + (size_t)(rM0 + row) * K + k0 + sj * 8);
        }
    };
    auto loadW = [&](int c, int k0) {
        const int row = c * 32 + srow;
        if constexpr (CVT_W) {
            const float* p = (const float*)W_ + (size_t)(c0 + row) * K + k0 + sj * 8;
            pwf[c][0] = ((const float4*)p)[0];
            pwf[c][1] = ((const float4*)p)[1];
        } else {
            pwb[c] = *(const bf16x8*)((const short*)W_ + (size_t)(c0 + row) * K + k0 + sj * 8);
        }
    };

#pragma unroll
    for (int c = 0; c < 4; ++c) { loadA(c, 0); loadW(c, 0); }

    int k0 = 0;
    for (;;) {
        __syncthreads();
#pragma unroll
        for (int c = 0; c < 4; ++c) {
            const int row = c * 32 + srow;
            const int pc = sj ^ (row & 7);
            if constexpr (CVT_A) *(bf16x8*)(&As[row * 64 + pc * 8]) = pack8(paf[c][0], paf[c][1]);
            else                 *(bf16x8*)(&As[row * 64 + pc * 8]) = pab[c];
            if constexpr (CVT_W) *(bf16x8*)(&Ws[row * 64 + pc * 8]) = pack8(pwf[c][0], pwf[c][1]);
            else                 *(bf16x8*)(&Ws[row * 64 + pc * 8]) = pwb[c];
        }
        __syncthreads();
        const int kn = k0 + 64;
        if (kn < K) {
#pragma unroll
            for (int c = 0; c < 4; ++c) { loadA(c, kn); loadW(c, kn); }
        }
#pragma unroll
        for (int kh = 0; kh < 2; ++kh) {
            bf16x8 af[4], bfv[4];
#pragma unroll
            for (int t = 0; t < 4; ++t) {
                const int ra = wm * 64 + t * 16 + low;
                af[t] = *(const bf16x8*)(&As[ra * 64 + ((kh * 4 + quad) ^ (ra & 7)) * 8]);
                const int rb = wn * 64 + t * 16 + low;
                bfv[t] = *(const bf16x8*)(&Ws[rb * 64 + ((kh * 4 + quad) ^ (rb & 7)) * 8]);
            }
#pragma unroll
            for (int mt = 0; mt < 4; ++mt)
#pragma unroll
                for (int nt = 0; nt < 4; ++nt)
                    acc[mt][nt] = __builtin_amdgcn_mfma_f32_16x16x32_bf16(af[mt], bfv[nt], acc[mt][nt], 0, 0, 0);
        }
        k0 = kn;
        if (k0 >= K) break;
    }

#pragma unroll
    for (int nt = 0; nt < 4; ++nt) {
        const int col = c0 + wn * 64 + nt * 16 + low;
        const float bv = bias[col];
#pragma unroll
        for (int mt = 0; mt < 4; ++mt) {
            const size_t rbase = (size_t)(rM0 + wm * 64 + mt * 16 + quad * 4);
#pragma unroll
            for (int r = 0; r < 4; ++r) {
                const float val = (acc[mt][nt][r] + bv) * scale;
                if (OUT_BF16) ((short*)out)[(rbase + r) * Ccols + col] = f2bf(val);
                else          ((float*)out)[(rbase + r) * Ccols + col] = val;
            }
        }
    }
}

// ---------------------------------------------------------------------------
// 64x64-tile bf16 MFMA GEMM (for skinny N) — same scheme, 4 waves in 2x2,
// each wave 32x32. Optional fused conversion.
// ---------------------------------------------------------------------------
template <bool CVT_A, bool CVT_W, bool OUT_BF16>
__global__ __launch_bounds__(256) void gemm64(
    const void* __restrict__ A_, const void* __restrict__ W_,
    const float* __restrict__ bias, void* __restrict__ out,
    int K, int Ccols, float scale)
{
    __shared__ short As[64 * 64];
    __shared__ short Ws[64 * 64];
    const int tid = threadIdx.x;
    const int w = tid >> 6, lane = tid & 63, low = lane & 15, quad = lane >> 4;
    const int wm = w >> 1, wn = w & 1;
    const int r0 = blockIdx.y * 64, c0 = blockIdx.x * 64;
    const int srow = tid >> 2;          // 0..63
    const int sc = (tid & 3) * 2;       // chunk pair {0,2,4,6}

    f32x4 acc[2][2];
#pragma unroll
    for (int mt = 0; mt < 2; ++mt)
#pragma unroll
        for (int nt = 0; nt < 2; ++nt) acc[mt][nt] = (f32x4){0.f, 0.f, 0.f, 0.f};

    float4 paf[2][2], pwf[2][2];
    bf16x8 pab[2], pwb[2];

    auto loadA = [&](int k0) {
        if constexpr (CVT_A) {
            const float* p = (const float*)A_ + (size_t)(r0 + srow) * K + k0 + sc * 8;
            paf[0][0] = ((const float4*)p)[0]; paf[0][1] = ((const float4*)p)[1];
            paf[1][0] = ((const float4*)p)[2]; paf[1][1] = ((const float4*)p)[3];
        } else {
            const short* p = (const short*)A_ + (size_t)(r0 + srow) * K + k0 + sc * 8;
            pab[0] = ((const bf16x8*)p)[0];
            pab[1] = ((const bf16x8*)p)[1];
        }
    };
    auto loadW = [&](int k0) {
        if constexpr (CVT_W) {
            const float* p = (const float*)W_ + (size_t)(c0 + srow) * K + k0 + sc * 8;
            pwf[0][0] = ((const float4*)p)[0]; pwf[0][1] = ((const float4*)p)[1];
            pwf[1][0] = ((const float4*)p)[2]; pwf[1][1] = ((const float4*)p)[3];
        } else {
            const short* p = (const short*)W_ + (size_t)(c0 + srow) * K + k0 + sc * 8;
            pwb[0] = ((const bf16x8*)p)[0];
            pwb[1] = ((const bf16x8*)p)[1];
        }
    };

    loadA(0); loadW(0);

    int k0 = 0;
    for (;;) {
        __syncthreads();
#pragma unroll
        for (int c = 0; c < 2; ++c) {
            const int pc = (sc + c) ^ (srow & 7);
            if constexpr (CVT_A) *(bf16x8*)(&As[srow * 64 + pc * 8]) = pack8(paf[c][0], paf[c][1]);
            else                 *(bf16x8*)(&As[srow * 64 + pc * 8]) = pab[c];
            if constexpr (CVT_W) *(bf16x8*)(&Ws[srow * 64 + pc * 8]) = pack8(pwf[c][0], pwf[c][1]);
            else                 *(bf16x8*)(&Ws[srow * 64 + pc * 8]) = pwb[c];
        }
        __syncthreads();
        const int kn = k0 + 64;
        if (kn < K) { loadA(kn); loadW(kn); }
#pragma unroll
        for (int kh = 0; kh < 2; ++kh) {
            bf16x8 af[2], bfv[2];
#pragma unroll
            for (int t = 0; t < 2; ++t) {
                const int ra = wm * 32 + t * 16 + low;
                af[t] = *(const bf16x8*)(&As[ra * 64 + ((kh * 4 + quad) ^ (ra & 7)) * 8]);
                const int rb = wn * 32 + t * 16 + low;
                bfv[t] = *(const bf16x8*)(&Ws[rb * 64 + ((kh * 4 + quad) ^ (rb & 7)) * 8]);
            }
#pragma unroll
            for (int mt = 0; mt < 2; ++mt)
#pragma unroll
                for (int nt = 0; nt < 2; ++nt)
                    acc[mt][nt] = __builtin_amdgcn_mfma_f32_16x16x32_bf16(af[mt], bfv[nt], acc[mt][nt], 0, 0, 0);
        }
        k0 = kn;
        if (k0 >= K) break;
    }

#pragma unroll
    for (int nt = 0; nt < 2; ++nt) {
        const int col = c0 + wn * 32 + nt * 16 + low;
        const float bv = bias[col];
#pragma unroll
        for (int mt = 0; mt < 2; ++mt) {
            const size_t rbase = (size_t)(r0 + wm * 32 + mt * 16 + quad * 4);
#pragma unroll
            for (int r = 0; r < 4; ++r) {
                const float val = (acc[mt][nt][r] + bv) * scale;
                if (OUT_BF16) ((short*)out)[(rbase + r) * Ccols + col] = f2bf(val);
                else          ((float*)out)[(rbase + r) * Ccols + col] = val;
            }
        }
    }
}

// ---------------------------------------------------------------------------
// MFMA bf16 flash attention, static softmax (q pre-scaled by 0.125*log2e).
// Block: 256 thr = 4 waves; 64 queries/block (16/wave). j-tile = 64 keys.
// S^T = K Q^T  (A = K rows from Ks[key][dim], B = Q regs)
//   -> C: col = query (lane&15), row = key (quad*4+r)
//   -> lsum is one scalar per lane (query = low); P stores to Ps[query][key]
//      are contiguous b64.
// O = P V     (A = P from Ps[query][key] b128, B = V from Vt[dim][key] b128)
//   -> C: row = query (quad*4+r), col = dim (low)
// K/V global loads register-prefetched one iteration ahead.
// ---------------------------------------------------------------------------
#define KST 72
#define VST 72
#define PST 72

__global__ __launch_bounds__(256) void attn_mfma(
    const short* __restrict__ q2,   // (NB*SEQ) x 512 bf16 (pre-scaled)
    const short* __restrict__ kv2,  // (NB*SEQ) x 1024 bf16
    short* __restrict__ o)          // (NB*SEQ) x 512 bf16
{
    __shared__ short Ks[64 * KST];
    __shared__ short Vt[64 * VST];
    __shared__ short Ps[4][16 * PST];

    const int tid = threadIdx.x;
    const int w = tid >> 6;
    const int lane = tid & 63;
    const int low = lane & 15;
    const int quad = lane >> 4;

    const int bh = blockIdx.y;
    const int b = bh >> 3;
    const int h = bh & 7;
    const int iq0 = blockIdx.x * 64;

    // --- Q fragments (used as MFMA B operand) ---
    bf16x8 qf[2];
#pragma unroll
    for (int kh = 0; kh < 2; ++kh)
        qf[kh] = *(const bf16x8*)(q2 + (size_t)(b * SEQ + iq0 + w * 16 + low) * 512
                                  + h * 64 + kh * 32 + quad * 8);

    const short* kbase = kv2 + (size_t)(b * SEQ) * 1024 + h * 64;
    const short* vbase = kbase + 512;
    short* pw = &Ps[w][0];

    float lsum = 0.f;                 // query = low
    f32x4 oacc[4];                    // [dt], row = query quad*4+r
#pragma unroll
    for (int dt = 0; dt < 4; ++dt) oacc[dt] = (f32x4){0.f, 0.f, 0.f, 0.f};

    // staging indices
    const int krow = tid >> 2;          // key row 0..63
    const int kc = (tid & 3) * 16;      // dim chunk (shorts)
    const int vk4 = (tid & 15) * 4;     // key base (V^T)
    const int vd4 = (tid >> 4) * 4;     // dim base 0..60

    // --- prefetch jt = 0 ---
    bf16x8 pk0, pk1;
    bf16x4 pv0, pv1, pv2, pv3;
    {
        const short* ksrc = kbase + (size_t)krow * 1024 + kc;
        pk0 = *(const bf16x8*)(ksrc);
        pk1 = *(const bf16x8*)(ksrc + 8);
        const short* vs = vbase + (size_t)vk4 * 1024 + vd4;
        pv0 = *(const bf16x4*)(vs);
        pv1 = *(const bf16x4*)(vs + 1024);
        pv2 = *(const bf16x4*)(vs + 2048);
        pv3 = *(const bf16x4*)(vs + 3072);
    }

    for (int jt = 0; jt < SEQ / 64; ++jt) {
        __syncthreads();
        *(bf16x8*)(&Ks[krow * KST + kc]) = pk0;
        *(bf16x8*)(&Ks[krow * KST + kc + 8]) = pk1;
        {
            bf16x4 c0_, c1_, c2_, c3_;
            c0_[0] = pv0[0]; c0_[1] = pv1[0]; c0_[2] = pv2[0]; c0_[3] = pv3[0];
            c1_[0] = pv0[1]; c1_[1] = pv1[1]; c1_[2] = pv2[1]; c1_[3] = pv3[1];
            c2_[0] = pv0[2]; c2_[1] = pv1[2]; c2_[2] = pv2[2]; c2_[3] = pv3[2];
            c3_[0] = pv0[3]; c3_[1] = pv1[3]; c3_[2] = pv2[3]; c3_[3] = pv3[3];
            *(bf16x4*)(&Vt[(vd4 + 0) * VST + vk4]) = c0_;
            *(bf16x4*)(&Vt[(vd4 + 1) * VST + vk4]) = c1_;
            *(bf16x4*)(&Vt[(vd4 + 2) * VST + vk4]) = c2_;
            *(bf16x4*)(&Vt[(vd4 + 3) * VST + vk4]) = c3_;
        }
        __syncthreads();

        // prefetch next tile
        if (jt + 1 < SEQ / 64) {
            const short* ksrc = kbase + (size_t)((jt + 1) * 64 + krow) * 1024 + kc;
            pk0 = *(const bf16x8*)(ksrc);
            pk1 = *(const bf16x8*)(ksrc + 8);
            const short* vs = vbase + (size_t)((jt + 1) * 64 + vk4) * 1024 + vd4;
            pv0 = *(const bf16x4*)(vs);
            pv1 = *(const bf16x4*)(vs + 1024);
            pv2 = *(const bf16x4*)(vs + 2048);
            pv3 = *(const bf16x4*)(vs + 3072);
        }

        // --- S^T = K Q^T, P = exp2, lsum, b64 P stores ---
#pragma unroll
        for (int nt = 0; nt < 4; ++nt) {
            const bf16x8 kf0 = *(const bf16x8*)(&Ks[(nt * 16 + low) * KST + quad * 8]);
            const bf16x8 kf1 = *(const bf16x8*)(&Ks[(nt * 16 + low) * KST + 32 + quad * 8]);
            f32x4 s = (f32x4){0.f, 0.f, 0.f, 0.f};
            s = __builtin_amdgcn_mfma_f32_16x16x32_bf16(kf0, qf[0], s, 0, 0, 0);
            s = __builtin_amdgcn_mfma_f32_16x16x32_bf16(kf1, qf[1], s, 0, 0, 0);
            const float p0 = __builtin_amdgcn_exp2f(s[0]);
            const float p1 = __builtin_amdgcn_exp2f(s[1]);
            const float p2 = __builtin_amdgcn_exp2f(s[2]);
            const float p3 = __builtin_amdgcn_exp2f(s[3]);
            lsum += (p0 + p1) + (p2 + p3);
            uint2 u;
            u.x = pack2bf(p0, p1);
            u.y = pack2bf(p2, p3);
            *(uint2*)(&pw[low * PST + nt * 16 + quad * 4]) = u;
        }
        __builtin_amdgcn_wave_barrier();

        // --- O += P V ---
#pragma unroll
        for (int kb = 0; kb < 2; ++kb) {
            const bf16x8 pfr = *(const bf16x8*)(&pw[low * PST + kb * 32 + quad * 8]);
#pragma unroll
            for (int dt = 0; dt < 4; ++dt) {
                const bf16x8 vf = *(const bf16x8*)(&Vt[(dt * 16 + low) * VST + kb * 32 + quad * 8]);
                oacc[dt] = __builtin_amdgcn_mfma_f32_16x16x32_bf16(pfr, vf, oacc[dt], 0, 0, 0);
            }
        }
        __builtin_amdgcn_wave_barrier();
    }

    // --- epilogue ---
    lsum += __shfl_xor(lsum, 16);
    lsum += __shfl_xor(lsum, 32);      // all quad-copies now hold l(query=low)
    float linv[4];
#pragma unroll
    for (int r = 0; r < 4; ++r)
        linv[r] = 1.f / __shfl(lsum, quad * 4 + r);

    short* obase = o + (size_t)(b * SEQ + iq0 + w * 16 + quad * 4) * 512 + h * 64;
#pragma unroll
    for (int r = 0; r < 4; ++r)
#pragma unroll
        for (int dt = 0; dt < 4; ++dt)
            obase[(size_t)r * 512 + dt * 16 + low] = f2bf(oacc[dt][r] * linv[r]);
}

// ---------------------------------------------------------------------------
extern "C" void kernel_launch(void* const* d_in, const int* in_sizes, int n_in,
                              void* d_out, int out_size, void* d_ws, size_t ws_size,
                              hipStream_t stream) {
    const float* x   = (const float*)d_in[0];  // (4,2048,256)
    const float* ctx = (const float*)d_in[1];  // (4,2048,256)
    const float* Wq  = (const float*)d_in[2];  // (512,256)
    const float* bq  = (const float*)d_in[3];
    const float* Wkv = (const float*)d_in[4];  // (1024,256)
    const float* bkv = (const float*)d_in[5];
    const float* Wo  = (const float*)d_in[6];  // (256,512)
    const float* bo  = (const float*)d_in[7];
    float* out = (float*)d_out;                // (4,2048,256) fp32

    const int ROWS = NB * SEQ;                 // 8192
    short* q2b  = (short*)d_ws;                         // 8192*512
    short* kv2b = q2b + (size_t)ROWS * 512;             // 8192*1024
    short* owsb = kv2b + (size_t)ROWS * 1024;           // 8192*512

    const float qscale = 0.125f * 1.44269504088896f;   // softmax scale + log2e

    // q = x*Wq^T + bq (scaled), 64x64 tiles, fused cvt of both inputs
    gemm64<true, true, true><<<dim3(512 / 64, ROWS / 64), 256, 0, stream>>>(
        x, Wq, bq, q2b, 256, 512, qscale);
    // kv = ctx*Wkv^T + bkv, 128x128 tiles, fused cvt
    gemm128<true, true, true><<<dim3(1024 / 128, ROWS / 128), 256, 0, stream>>>(
        ctx, Wkv, bkv, kv2b, 256, 1024, 1.0f);
    attn_mfma<<<dim3(SEQ / 64, NB * NHEADS), 256, 0, stream>>>(q2b, kv2b, owsb);
    // out = ows*Wo^T + bo, 64x64 tiles, fused cvt of Wo, fp32 out
    gemm64<false, true, false><<<dim3(256 / 64, ROWS / 64), 256, 0, stream>>>(
        owsb, Wo, bo, out, 512, 256, 1.0f);
}

// Round 6
// 172.248 us; speedup vs baseline: 1.1211x; 1.1211x over previous
//
#include <hip/hip_runtime.h>
#include <hip/hip_bf16.h>

#define NB 4
#define SEQ 2048
#define NHEADS 8

typedef __attribute__((ext_vector_type(8))) short bf16x8;
typedef __attribute__((ext_vector_type(4))) short bf16x4;
typedef __attribute__((ext_vector_type(4))) float f32x4;

__device__ inline short f2bf(float x) {
    union { float f; unsigned u; } v; v.f = x;
    unsigned r = v.u + 0x7FFF + ((v.u >> 16) & 1);
    return (short)(r >> 16);
}

__device__ inline unsigned pack2bf(float a, float b) {
    __hip_bfloat162 h = __float22bfloat162_rn(make_float2(a, b));
    unsigned u; __builtin_memcpy(&u, &h, 4);
    return u;
}

__device__ inline bf16x8 pack8(float4 a, float4 b) {
    union { unsigned u[4]; bf16x8 v; } r;
    r.u[0] = pack2bf(a.x, a.y);
    r.u[1] = pack2bf(a.z, a.w);
    r.u[2] = pack2bf(b.x, b.y);
    r.u[3] = pack2bf(b.z, b.w);
    return r.v;
}

// ---------------------------------------------------------------------------
// fp32 -> bf16 cast for x and ctx (one launch). Unit = 4 elements.
// x: 524288 units, ctx: 524288 units -> 4096 blocks x 256.
// ---------------------------------------------------------------------------
__global__ __launch_bounds__(256) void cvt_xc(
    const float* __restrict__ x, const float* __restrict__ ctx,
    short* __restrict__ xb, short* __restrict__ cb)
{
    const int i = blockIdx.x * 256 + threadIdx.x;
    const float* src; short* dst; int off;
    if (i < 524288) { src = x;   dst = xb; off = i; }
    else            { src = ctx; dst = cb; off = i - 524288; }
    const float4 v = ((const float4*)src)[off];
    uint2 o2;
    o2.x = pack2bf(v.x, v.y);
    o2.y = pack2bf(v.z, v.w);
    *(uint2*)(dst + (size_t)off * 4) = o2;
}

// ---------------------------------------------------------------------------
// 128x128-tile bf16 MFMA GEMM, optional fused fp32->bf16 conversion of A/W.
// out[r][c] = (sum_k A[r][k]*W[c][k] + bias[c]) * scale
// 256 thr = 4 waves (2x2); XOR-swizzled unpadded LDS; register prefetch.
// ---------------------------------------------------------------------------
template <bool CVT_A, bool CVT_W, bool OUT_BF16>
__global__ __launch_bounds__(256) void gemm128(
    const void* __restrict__ A_, const void* __restrict__ W_,
    const float* __restrict__ bias, void* __restrict__ out,
    int K, int Ccols, float scale)
{
    __shared__ short As[128 * 64];
    __shared__ short Ws[128 * 64];
    const int tid = threadIdx.x;
    const int w = tid >> 6, lane = tid & 63, low = lane & 15, quad = lane >> 4;
    const int wm = w >> 1, wn = w & 1;
    const int rM0 = blockIdx.y * 128, c0 = blockIdx.x * 128;
    const int srow = tid >> 3, sj = tid & 7;

    f32x4 acc[4][4];
#pragma unroll
    for (int mt = 0; mt < 4; ++mt)
#pragma unroll
        for (int nt = 0; nt < 4; ++nt) acc[mt][nt] = (f32x4){0.f, 0.f, 0.f, 0.f};

    float4 paf[4][2], pwf[4][2];
    bf16x8 pab[4], pwb[4];

    auto loadA = [&](int c, int k0) {
        const int row = c * 32 + srow;
        if constexpr (CVT_A) {
            const float* p = (const float*)A_ + (size_t)(rM0 + row) * K + k0 + sj * 8;
            paf[c][0] = ((const float4*)p)[0];
            paf[c][1] = ((const float4*)p)[1];
        } else {
            pab[c] = *(const bf16x8*)((const short*)A_ + (size_t)(rM0 + row) * K + k0 + sj * 8);
        }
    };
    auto loadW = [&](int c, int k0) {
        const int row = c * 32 + srow;
        if constexpr (CVT_W) {
            const float* p = (const float*)W_ + (size_t)(c0 + row) * K + k0 + sj * 8;
            pwf[c][0] = ((const float4*)p)[0];
            pwf[c][1] = ((const float4*)p)[1];
        } else {
            pwb[c] = *(const bf16x8*)((const short*)W_ + (size_t)(c0 + row) * K + k0 + sj * 8);
        }
    };

#pragma unroll
    for (int c = 0; c < 4; ++c) { loadA(c, 0); loadW(c, 0); }

    int k0 = 0;
    for (;;) {
        __syncthreads();
#pragma unroll
        for (int c = 0; c < 4; ++c) {
            const int row = c * 32 + srow;
            const int pc = sj ^ (row & 7);
            if constexpr (CVT_A) *(bf16x8*)(&As[row * 64 + pc * 8]) = pack8(paf[c][0], paf[c][1]);
            else                 *(bf16x8*)(&As[row * 64 + pc * 8]) = pab[c];
            if constexpr (CVT_W) *(bf16x8*)(&Ws[row * 64 + pc * 8]) = pack8(pwf[c][0], pwf[c][1]);
            else                 *(bf16x8*)(&Ws[row * 64 + pc * 8]) = pwb[c];
        }
        __syncthreads();
        const int kn = k0 + 64;
        if (kn < K) {
#pragma unroll
            for (int c = 0; c < 4; ++c) { loadA(c, kn); loadW(c, kn); }
        }
#pragma unroll
        for (int kh = 0; kh < 2; ++kh) {
            bf16x8 af[4], bfv[4];
#pragma unroll
            for (int t = 0; t < 4; ++t) {
                const int ra = wm * 64 + t * 16 + low;
                af[t] = *(const bf16x8*)(&As[ra * 64 + ((kh * 4 + quad) ^ (ra & 7)) * 8]);
                const int rb = wn * 64 + t * 16 + low;
                bfv[t] = *(const bf16x8*)(&Ws[rb * 64 + ((kh * 4 + quad) ^ (rb & 7)) * 8]);
            }
#pragma unroll
            for (int mt = 0; mt < 4; ++mt)
#pragma unroll
                for (int nt = 0; nt < 4; ++nt)
                    acc[mt][nt] = __builtin_amdgcn_mfma_f32_16x16x32_bf16(af[mt], bfv[nt], acc[mt][nt], 0, 0, 0);
        }
        k0 = kn;
        if (k0 >= K) break;
    }

#pragma unroll
    for (int nt = 0; nt < 4; ++nt) {
        const int col = c0 + wn * 64 + nt * 16 + low;
        const float bv = bias[col];
#pragma unroll
        for (int mt = 0; mt < 4; ++mt) {
            const size_t rbase = (size_t)(rM0 + wm * 64 + mt * 16 + quad * 4);
#pragma unroll
            for (int r = 0; r < 4; ++r) {
                const float val = (acc[mt][nt][r] + bv) * scale;
                if (OUT_BF16) ((short*)out)[(rbase + r) * Ccols + col] = f2bf(val);
                else          ((float*)out)[(rbase + r) * Ccols + col] = val;
            }
        }
    }
}

// ---------------------------------------------------------------------------
// 64x64-tile bf16 MFMA GEMM (skinny N) — 4 waves 2x2, wave 32x32.
// ---------------------------------------------------------------------------
template <bool CVT_A, bool CVT_W, bool OUT_BF16>
__global__ __launch_bounds__(256) void gemm64(
    const void* __restrict__ A_, const void* __restrict__ W_,
    const float* __restrict__ bias, void* __restrict__ out,
    int K, int Ccols, float scale)
{
    __shared__ short As[64 * 64];
    __shared__ short Ws[64 * 64];
    const int tid = threadIdx.x;
    const int w = tid >> 6, lane = tid & 63, low = lane & 15, quad = lane >> 4;
    const int wm = w >> 1, wn = w & 1;
    const int r0 = blockIdx.y * 64, c0 = blockIdx.x * 64;
    const int srow = tid >> 2;
    const int sc = (tid & 3) * 2;

    f32x4 acc[2][2];
#pragma unroll
    for (int mt = 0; mt < 2; ++mt)
#pragma unroll
        for (int nt = 0; nt < 2; ++nt) acc[mt][nt] = (f32x4){0.f, 0.f, 0.f, 0.f};

    float4 paf[2][2], pwf[2][2];
    bf16x8 pab[2], pwb[2];

    auto loadA = [&](int k0) {
        if constexpr (CVT_A) {
            const float* p = (const float*)A_ + (size_t)(r0 + srow) * K + k0 + sc * 8;
            paf[0][0] = ((const float4*)p)[0]; paf[0][1] = ((const float4*)p)[1];
            paf[1][0] = ((const float4*)p)[2]; paf[1][1] = ((const float4*)p)[3];
        } else {
            const short* p = (const short*)A_ + (size_t)(r0 + srow) * K + k0 + sc * 8;
            pab[0] = ((const bf16x8*)p)[0];
            pab[1] = ((const bf16x8*)p)[1];
        }
    };
    auto loadW = [&](int k0) {
        if constexpr (CVT_W) {
            const float* p = (const float*)W_ + (size_t)(c0 + srow) * K + k0 + sc * 8;
            pwf[0][0] = ((const float4*)p)[0]; pwf[0][1] = ((const float4*)p)[1];
            pwf[1][0] = ((const float4*)p)[2]; pwf[1][1] = ((const float4*)p)[3];
        } else {
            const short* p = (const short*)W_ + (size_t)(c0 + srow) * K + k0 + sc * 8;
            pwb[0] = ((const bf16x8*)p)[0];
            pwb[1] = ((const bf16x8*)p)[1];
        }
    };

    loadA(0); loadW(0);

    int k0 = 0;
    for (;;) {
        __syncthreads();
#pragma unroll
        for (int c = 0; c < 2; ++c) {
            const int pc = (sc + c) ^ (srow & 7);
            if constexpr (CVT_A) *(bf16x8*)(&As[srow * 64 + pc * 8]) = pack8(paf[c][0], paf[c][1]);
            else                 *(bf16x8*)(&As[srow * 64 + pc * 8]) = pab[c];
            if constexpr (CVT_W) *(bf16x8*)(&Ws[srow * 64 + pc * 8]) = pack8(pwf[c][0], pwf[c][1]);
            else                 *(bf16x8*)(&Ws[srow * 64 + pc * 8]) = pwb[c];
        }
        __syncthreads();
        const int kn = k0 + 64;
        if (kn < K) { loadA(kn); loadW(kn); }
#pragma unroll
        for (int kh = 0; kh < 2; ++kh) {
            bf16x8 af[2], bfv[2];
#pragma unroll
            for (int t = 0; t < 2; ++t) {
                const int ra = wm * 32 + t * 16 + low;
                af[t] = *(const bf16x8*)(&As[ra * 64 + ((kh * 4 + quad) ^ (ra & 7)) * 8]);
                const int rb = wn * 32 + t * 16 + low;
                bfv[t] = *(const bf16x8*)(&Ws[rb * 64 + ((kh * 4 + quad) ^ (rb & 7)) * 8]);
            }
#pragma unroll
            for (int mt = 0; mt < 2; ++mt)
#pragma unroll
                for (int nt = 0; nt < 2; ++nt)
                    acc[mt][nt] = __builtin_amdgcn_mfma_f32_16x16x32_bf16(af[mt], bfv[nt], acc[mt][nt], 0, 0, 0);
        }
        k0 = kn;
        if (k0 >= K) break;
    }

#pragma unroll
    for (int nt = 0; nt < 2; ++nt) {
        const int col = c0 + wn * 32 + nt * 16 + low;
        const float bv = bias[col];
#pragma unroll
        for (int mt = 0; mt < 2; ++mt) {
            const size_t rbase = (size_t)(r0 + wm * 32 + mt * 16 + quad * 4);
#pragma unroll
            for (int r = 0; r < 4; ++r) {
                const float val = (acc[mt][nt][r] + bv) * scale;
                if (OUT_BF16) ((short*)out)[(rbase + r) * Ccols + col] = f2bf(val);
                else          ((float*)out)[(rbase + r) * Ccols + col] = val;
            }
        }
    }
}

// ---------------------------------------------------------------------------
// MFMA bf16 flash attention, static softmax (q pre-scaled by 0.125*log2e).
// Block: 256 thr = 4 waves; 128 queries/block, 32/wave (qt in {0,1} x 16).
// Grid: 1-D, XCD-swizzled: flat = h + 8*(qtile + 16*b) -> all 16 qtiles of a
// given (b,h) share flat%8, i.e. one XCD (round-robin dispatch) -> kv slice
// (0.5 MB) stays L2-resident across its 16 blocks.
// S^T = K Q^T per qt (A = K rows from Ks[key][dim], B = Q regs)
//   -> C: col = query (low), row = key (quad*4+r); lsum scalar per lane/qt;
//      P stores contiguous b64 into Ps[query][key].
// O = P V  (A = P b128, B = V from Vt[dim][key] b128)
//   -> C: row = query (quad*4+r), col = dim (low). No epilogue transpose.
// K/V global loads register-prefetched one iteration ahead.
// ---------------------------------------------------------------------------
#define KST 72
#define VST 72
#define PST 72

__global__ __launch_bounds__(256) void attn_mfma(
    const short* __restrict__ q2,   // (NB*SEQ) x 512 bf16 (pre-scaled)
    const short* __restrict__ kv2,  // (NB*SEQ) x 1024 bf16
    short* __restrict__ o)          // (NB*SEQ) x 512 bf16
{
    __shared__ short Ks[64 * KST];
    __shared__ short Vt[64 * VST];
    __shared__ short Ps[4][32 * PST];

    const int tid = threadIdx.x;
    const int w = tid >> 6;
    const int lane = tid & 63;
    const int low = lane & 15;
    const int quad = lane >> 4;

    // XCD swizzle decode
    const int flat = blockIdx.x;
    const int h = flat & 7;
    const int rest = flat >> 3;
    const int qtile = rest & 15;
    const int b = rest >> 4;
    const int iq0 = qtile * 128;

    // --- Q fragments (B operand; registers whole kernel) ---
    bf16x8 qf[2][2];
#pragma unroll
    for (int qt = 0; qt < 2; ++qt)
#pragma unroll
        for (int kh = 0; kh < 2; ++kh)
            qf[qt][kh] = *(const bf16x8*)(q2 + (size_t)(b * SEQ + iq0 + w * 32 + qt * 16 + low) * 512
                                          + h * 64 + kh * 32 + quad * 8);

    const short* kbase = kv2 + (size_t)(b * SEQ) * 1024 + h * 64;
    const short* vbase = kbase + 512;
    short* pw = &Ps[w][0];

    float lsum[2] = {0.f, 0.f};       // per lane: query = low, per qt
    f32x4 oacc[2][4];                 // [qt][dt], row = query quad*4+r
#pragma unroll
    for (int qt = 0; qt < 2; ++qt)
#pragma unroll
        for (int dt = 0; dt < 4; ++dt) oacc[qt][dt] = (f32x4){0.f, 0.f, 0.f, 0.f};

    // staging indices
    const int krow = tid >> 2;          // key row 0..63
    const int kc = (tid & 3) * 16;      // dim chunk (shorts)
    const int vk4 = (tid & 15) * 4;     // key base (V^T)
    const int vd4 = (tid >> 4) * 4;     // dim base 0..60

    // --- prefetch jt = 0 ---
    bf16x8 pk0, pk1;
    bf16x4 pv0, pv1, pv2, pv3;
    {
        const short* ksrc = kbase + (size_t)krow * 1024 + kc;
        pk0 = *(const bf16x8*)(ksrc);
        pk1 = *(const bf16x8*)(ksrc + 8);
        const short* vs = vbase + (size_t)vk4 * 1024 + vd4;
        pv0 = *(const bf16x4*)(vs);
        pv1 = *(const bf16x4*)(vs + 1024);
        pv2 = *(const bf16x4*)(vs + 2048);
        pv3 = *(const bf16x4*)(vs + 3072);
    }

    for (int jt = 0; jt < SEQ / 64; ++jt) {
        __syncthreads();
        *(bf16x8*)(&Ks[krow * KST + kc]) = pk0;
        *(bf16x8*)(&Ks[krow * KST + kc + 8]) = pk1;
        {
            bf16x4 c0_, c1_, c2_, c3_;
            c0_[0] = pv0[0]; c0_[1] = pv1[0]; c0_[2] = pv2[0]; c0_[3] = pv3[0];
            c1_[0] = pv0[1]; c1_[1] = pv1[1]; c1_[2] = pv2[1]; c1_[3] = pv3[1];
            c2_[0] = pv0[2]; c2_[1] = pv1[2]; c2_[2] = pv2[2]; c2_[3] = pv3[2];
            c3_[0] = pv0[3]; c3_[1] = pv1[3]; c3_[2] = pv2[3]; c3_[3] = pv3[3];
            *(bf16x4*)(&Vt[(vd4 + 0) * VST + vk4]) = c0_;
            *(bf16x4*)(&Vt[(vd4 + 1) * VST + vk4]) = c1_;
            *(bf16x4*)(&Vt[(vd4 + 2) * VST + vk4]) = c2_;
            *(bf16x4*)(&Vt[(vd4 + 3) * VST + vk4]) = c3_;
        }
        __syncthreads();

        // prefetch next tile
        if (jt + 1 < SEQ / 64) {
            const short* ksrc = kbase + (size_t)((jt + 1) * 64 + krow) * 1024 + kc;
            pk0 = *(const bf16x8*)(ksrc);
            pk1 = *(const bf16x8*)(ksrc + 8);
            const short* vs = vbase + (size_t)((jt + 1) * 64 + vk4) * 1024 + vd4;
            pv0 = *(const bf16x4*)(vs);
            pv1 = *(const bf16x4*)(vs + 1024);
            pv2 = *(const bf16x4*)(vs + 2048);
            pv3 = *(const bf16x4*)(vs + 3072);
        }

        // --- S^T = K Q^T, P = exp2, lsum, b64 P stores ---
#pragma unroll
        for (int nt = 0; nt < 4; ++nt) {
            const bf16x8 kf0 = *(const bf16x8*)(&Ks[(nt * 16 + low) * KST + quad * 8]);
            const bf16x8 kf1 = *(const bf16x8*)(&Ks[(nt * 16 + low) * KST + 32 + quad * 8]);
#pragma unroll
            for (int qt = 0; qt < 2; ++qt) {
                f32x4 s = (f32x4){0.f, 0.f, 0.f, 0.f};
                s = __builtin_amdgcn_mfma_f32_16x16x32_bf16(kf0, qf[qt][0], s, 0, 0, 0);
                s = __builtin_amdgcn_mfma_f32_16x16x32_bf16(kf1, qf[qt][1], s, 0, 0, 0);
                const float p0 = __builtin_amdgcn_exp2f(s[0]);
                const float p1 = __builtin_amdgcn_exp2f(s[1]);
                const float p2 = __builtin_amdgcn_exp2f(s[2]);
                const float p3 = __builtin_amdgcn_exp2f(s[3]);
                lsum[qt] += (p0 + p1) + (p2 + p3);
                uint2 u;
                u.x = pack2bf(p0, p1);
                u.y = pack2bf(p2, p3);
                *(uint2*)(&pw[(qt * 16 + low) * PST + nt * 16 + quad * 4]) = u;
            }
        }
        __builtin_amdgcn_wave_barrier();

        // --- O += P V ---
#pragma unroll
        for (int kb = 0; kb < 2; ++kb) {
            bf16x8 pfr[2];
#pragma unroll
            for (int qt = 0; qt < 2; ++qt)
                pfr[qt] = *(const bf16x8*)(&pw[(qt * 16 + low) * PST + kb * 32 + quad * 8]);
#pragma unroll
            for (int dt = 0; dt < 4; ++dt) {
                const bf16x8 vf = *(const bf16x8*)(&Vt[(dt * 16 + low) * VST + kb * 32 + quad * 8]);
                oacc[0][dt] = __builtin_amdgcn_mfma_f32_16x16x32_bf16(pfr[0], vf, oacc[0][dt], 0, 0, 0);
                oacc[1][dt] = __builtin_amdgcn_mfma_f32_16x16x32_bf16(pfr[1], vf, oacc[1][dt], 0, 0, 0);
            }
        }
        __builtin_amdgcn_wave_barrier();
    }

    // --- epilogue: reduce l over quads (copies of query=low), store ---
#pragma unroll
    for (int qt = 0; qt < 2; ++qt) {
        float lv = lsum[qt];
        lv += __shfl_xor(lv, 16);
        lv += __shfl_xor(lv, 32);      // every lane: l(query = its low)
        float linv[4];
#pragma unroll
        for (int r = 0; r < 4; ++r)
            linv[r] = 1.f / __shfl(lv, quad * 4 + r);
        short* obase = o + (size_t)(b * SEQ + iq0 + w * 32 + qt * 16 + quad * 4) * 512 + h * 64;
#pragma unroll
        for (int r = 0; r < 4; ++r)
#pragma unroll
            for (int dt = 0; dt < 4; ++dt)
                obase[(size_t)r * 512 + dt * 16 + low] = f2bf(oacc[qt][dt][r] * linv[r]);
    }
}

// ---------------------------------------------------------------------------
extern "C" void kernel_launch(void* const* d_in, const int* in_sizes, int n_in,
                              void* d_out, int out_size, void* d_ws, size_t ws_size,
                              hipStream_t stream) {
    const float* x   = (const float*)d_in[0];  // (4,2048,256)
    const float* ctx = (const float*)d_in[1];  // (4,2048,256)
    const float* Wq  = (const float*)d_in[2];  // (512,256)
    const float* bq  = (const float*)d_in[3];
    const float* Wkv = (const float*)d_in[4];  // (1024,256)
    const float* bkv = (const float*)d_in[5];
    const float* Wo  = (const float*)d_in[6];  // (256,512)
    const float* bo  = (const float*)d_in[7];
    float* out = (float*)d_out;                // (4,2048,256) fp32

    const int ROWS = NB * SEQ;                 // 8192
    short* xb   = (short*)d_ws;                         // 8192*256
    short* cb   = xb + (size_t)ROWS * 256;              // 8192*256
    short* q2b  = cb + (size_t)ROWS * 256;              // 8192*512
    short* kv2b = q2b + (size_t)ROWS * 512;             // 8192*1024
    short* owsb = kv2b + (size_t)ROWS * 1024;           // 8192*512

    const float qscale = 0.125f * 1.44269504088896f;   // softmax scale + log2e

    cvt_xc<<<4096, 256, 0, stream>>>(x, ctx, xb, cb);

    // q = x*Wq^T + bq (scaled): 64x64 tiles, bf16 A, cvt W
    gemm64<false, true, true><<<dim3(512 / 64, ROWS / 64), 256, 0, stream>>>(
        xb, Wq, bq, q2b, 256, 512, qscale);
    // kv = ctx*Wkv^T + bkv: 128x128 tiles, bf16 A, cvt W
    gemm128<false, true, true><<<dim3(1024 / 128, ROWS / 128), 256, 0, stream>>>(
        cb, Wkv, bkv, kv2b, 256, 1024, 1.0f);
    // attention, XCD-swizzled 1-D grid
    attn_mfma<<<NB * NHEADS * (SEQ / 128), 256, 0, stream>>>(q2b, kv2b, owsb);
    // out = ows*Wo^T + bo: 64x64 tiles, cvt W, fp32 out
    gemm64<false, true, false><<<dim3(256 / 64, ROWS / 64), 256, 0, stream>>>(
        owsb, Wo, bo, out, 512, 256, 1.0f);
}